// Round 5
// baseline (293.013 us; speedup 1.0000x reference)
//
#include <hip/hip_runtime.h>
#include <cstddef>

// ---------------- problem constants (match reference) ----------------
#define NB   4
#define NN_  6
#define ND_  41
#define NFH  16
#define NFW  44
#define NC   64
#define NX0_ 200
#define NX1_ 200
#define NXY  (NX0_ * NX1_)                 // 40000
#define NCOL (NB * NN_ * ND_ * NFW)        // 43296 columns (each = 16 vertical pixels)
#define NCELL (NB * NXY)                   // 160000 BEV cells
#define CAP   48                           // max entries per cell (est. worst ~17)
#define QMAX  (64 * CAP)                   // per-tile queue bound (by construction)

// 3x3 inverse via adjugate. For these inputs (integer pinhole K, identity
// post_rots) every cofactor/det is exact in f32 and each division correctly
// rounded -> matches numpy's inv bit-for-bit. (Validated rounds 1-2.)
__device__ __forceinline__ void inv3(const float* a, float* inv) {
    float c00 = __fsub_rn(__fmul_rn(a[4], a[8]), __fmul_rn(a[5], a[7]));
    float c01 = __fsub_rn(__fmul_rn(a[5], a[6]), __fmul_rn(a[3], a[8]));
    float c02 = __fsub_rn(__fmul_rn(a[3], a[7]), __fmul_rn(a[4], a[6]));
    float det = __fadd_rn(__fadd_rn(__fmul_rn(a[0], c00), __fmul_rn(a[1], c01)),
                          __fmul_rn(a[2], c02));
    inv[0] = __fdiv_rn(c00, det);
    inv[1] = __fdiv_rn(__fsub_rn(__fmul_rn(a[2], a[7]), __fmul_rn(a[1], a[8])), det);
    inv[2] = __fdiv_rn(__fsub_rn(__fmul_rn(a[1], a[5]), __fmul_rn(a[2], a[4])), det);
    inv[3] = __fdiv_rn(c01, det);
    inv[4] = __fdiv_rn(__fsub_rn(__fmul_rn(a[0], a[8]), __fmul_rn(a[2], a[6])), det);
    inv[5] = __fdiv_rn(__fsub_rn(__fmul_rn(a[2], a[3]), __fmul_rn(a[0], a[5])), det);
    inv[6] = __fdiv_rn(c02, det);
    inv[7] = __fdiv_rn(__fsub_rn(__fmul_rn(a[1], a[6]), __fmul_rn(a[0], a[7])), det);
    inv[8] = __fdiv_rn(__fsub_rn(__fmul_rn(a[0], a[4]), __fmul_rn(a[1], a[3])), det);
}

__global__ void setup_kernel(const float* __restrict__ rots,
                             const float* __restrict__ trans,
                             const float* __restrict__ intrins,
                             const float* __restrict__ post_rots,
                             const float* __restrict__ post_trans,
                             float* __restrict__ mats) {
    int t = threadIdx.x;
    if (t >= NB * NN_) return;
    const float* R  = rots      + t * 9;
    const float* K  = intrins   + t * 9;
    const float* PR = post_rots + t * 9;
    float Kinv[9], Pinv[9];
    inv3(K, Kinv);
    inv3(PR, Pinv);
    float* o = mats + t * 24;
    for (int i = 0; i < 3; ++i)
        for (int k = 0; k < 3; ++k) {
            float s = __fmul_rn(R[i * 3 + 0], Kinv[0 * 3 + k]);
            s = __fadd_rn(s, __fmul_rn(R[i * 3 + 1], Kinv[1 * 3 + k]));
            s = __fadd_rn(s, __fmul_rn(R[i * 3 + 2], Kinv[2 * 3 + k]));
            o[i * 3 + k] = s;
        }
    for (int i = 0; i < 9; ++i) o[9 + i] = Pinv[i];
    o[18] = trans[t * 3 + 0];
    o[19] = trans[t * 3 + 1];
    o[20] = trans[t * 3 + 2];
    o[21] = post_trans[t * 3 + 0];
    o[22] = post_trans[t * 3 + 1];
    o[23] = post_trans[t * 3 + 2];
}

// Fire-and-forget hardware FP32 atomic add (fallback path only).
__device__ __forceinline__ void hw_fadd(float* p, float v) {
    asm volatile("global_atomic_add_f32 %0, %1, off" : : "v"(p), "v"(v) : "memory");
}

// Voxel flat index (b*NXY + i0*NX1 + i1) for point (b,n,d,h,w), or -1.
// Numerics IDENTICAL to the passing rounds: _rn intrinsics only (no fma
// contraction), f64 linspace semantics for u, trunc-toward-zero.
__device__ __forceinline__ int compute_idx(int b, int n, int d, int h, int w,
                                           const float* __restrict__ mats) {
    const float* mp = mats + (b * NN_ + n) * 24;

    float u   = (w == NFW - 1) ? 703.0f : (float)((double)w * (703.0 / 43.0));
    float v   = __fmul_rn((float)h, 17.0f);   // 255/15 == 17 exactly
    float dep = (float)(4 + d);               // arange(4,45,1): exact ints

    float f0 = __fsub_rn(u, mp[21]);
    float f1 = __fsub_rn(v, mp[22]);
    float f2 = __fsub_rn(dep, mp[23]);

    float q0 = __fadd_rn(__fadd_rn(__fmul_rn(mp[9],  f0), __fmul_rn(mp[10], f1)), __fmul_rn(mp[11], f2));
    float q1 = __fadd_rn(__fadd_rn(__fmul_rn(mp[12], f0), __fmul_rn(mp[13], f1)), __fmul_rn(mp[14], f2));
    float q2 = __fadd_rn(__fadd_rn(__fmul_rn(mp[15], f0), __fmul_rn(mp[16], f1)), __fmul_rn(mp[17], f2));

    float r0 = __fmul_rn(q0, q2);
    float r1 = __fmul_rn(q1, q2);

    float g0 = __fadd_rn(__fadd_rn(__fadd_rn(__fmul_rn(mp[0], r0), __fmul_rn(mp[1], r1)), __fmul_rn(mp[2], q2)), mp[18]);
    float g1 = __fadd_rn(__fadd_rn(__fadd_rn(__fmul_rn(mp[3], r0), __fmul_rn(mp[4], r1)), __fmul_rn(mp[5], q2)), mp[19]);
    float g2 = __fadd_rn(__fadd_rn(__fadd_rn(__fmul_rn(mp[6], r0), __fmul_rn(mp[7], r1)), __fmul_rn(mp[8], q2)), mp[20]);

    float s0 = __fdiv_rn(__fsub_rn(g0, -50.0f), 0.5f);
    float s1 = __fdiv_rn(__fsub_rn(g1, -50.0f), 0.5f);
    float s2 = __fdiv_rn(__fsub_rn(g2, -10.0f), 20.0f);
    s0 = fminf(fmaxf(s0, -1e6f), 1e6f);
    s1 = fminf(fmaxf(s1, -1e6f), 1e6f);
    s2 = fminf(fmaxf(s2, -1e6f), 1e6f);
    int i0 = (int)s0;   // trunc toward zero == jnp.trunc().astype(int32)
    int i1 = (int)s1;
    int i2 = (int)s2;
    if (i0 >= 0 && i0 < NX0_ && i1 >= 0 && i1 < NX1_ && i2 >= 0 && i2 < 1)
        return b * NXY + i0 * NX1_ + i1;
    return -1;
}

// Invert the scatter: one thread per (b,n,d,w) column computes its cell and
// 16-bit h-validity mask, appends (hmask<<16 | cid_low16) to the cell's list
// (cid < 65536, and the cell id itself pins b). Fast path: all valid h share
// one cell (true for these inputs: BEV cell is h-independent). Rare path
// (h-dependent cells): per-h singleton entries — correct, never taken here.
__global__ __launch_bounds__(256) void build_lists(const float* __restrict__ mats,
                                                   int* __restrict__ cnt,
                                                   unsigned* __restrict__ lists) {
    int cid = blockIdx.x * 256 + threadIdx.x;
    if (cid >= NCOL) return;
    int w = cid % NFW; int t = cid / NFW;
    int d = t % ND_;   t /= ND_;
    int n = t % NN_;   int b = t / NN_;

    int first = -1;
    unsigned vm = 0, sm = 0;
    #pragma unroll
    for (int h = 0; h < 16; ++h) {
        int ih = compute_idx(b, n, d, h, w, mats);
        bool val = (ih >= 0);
        vm |= (val ? 1u : 0u) << h;
        if (first < 0 && val) first = ih;
        sm |= ((val && ih == first) ? 1u : 0u) << h;
    }
    if (vm == 0) return;
    if (sm == vm) {                        // single cell for the whole column
        int slot = atomicAdd(&cnt[first], 1);
        if (slot < CAP) lists[(size_t)first * CAP + slot] = (vm << 16) | (unsigned)(cid & 0xffff);
    } else {                               // safety net (unreachable here)
        #pragma unroll
        for (int h = 0; h < 16; ++h) {
            int ih = compute_idx(b, n, d, h, w, mats);
            if (ih >= 0) {
                int slot = atomicAdd(&cnt[ih], 1);
                if (slot < CAP) lists[(size_t)ih * CAP + slot] = (1u << (16 + h)) | (unsigned)(cid & 0xffff);
            }
        }
    }
}

// One block per (64-cell xy strip, b). Entries of all 64 cells are flattened
// into a block-wide LDS queue and round-robined over the 16 lane-groups
// (load balance: hot near-field cells spread across groups). Each entry:
// lane l sums channels [4l,4l+4) over the masked h rows of x (coalesced
// 256B/row), then ds_add_f32 into the XOR-swizzled tile (<=2-way banks =
// free, m136). Write phase = validated transpose_ws epilogue: fully-
// coalesced float4, writes every out element (zeros included) -> replaces
// the output memset. No global float atomics anywhere.
__global__ __launch_bounds__(256) void gather_bev(const float* __restrict__ x,
                                                  const int* __restrict__ cnt,
                                                  const unsigned* __restrict__ lists,
                                                  float* __restrict__ out) {
    __shared__ float4 tile[64 * 16];          // [cell][c4 ^ ((cell>>2)&15)], 16 KB
    __shared__ unsigned short items[QMAX];    // (ci<<8)|e, 6 KB; bounded by construction
    __shared__ int qcount;

    int b   = blockIdx.y;
    int xy0 = blockIdx.x * 64;

    if (threadIdx.x == 0) qcount = 0;
    #pragma unroll
    for (int s = 0; s < 4; ++s)
        tile[s * 256 + threadIdx.x] = make_float4(0.f, 0.f, 0.f, 0.f);
    __syncthreads();

    if (threadIdx.x < 64) {
        int ci = threadIdx.x;
        int c  = cnt[b * NXY + xy0 + ci];
        c = c < CAP ? c : CAP;
        if (c > 0) {
            int base = atomicAdd(&qcount, c);
            for (int e = 0; e < c; ++e)
                items[base + e] = (unsigned short)((ci << 8) | e);
        }
    }
    __syncthreads();
    int total = qcount;

    int g = threadIdx.x >> 4;                 // lane-group 0..15
    int l = threadIdx.x & 15;                 // channel quad
    const int HS = NFW * (NC / 4);            // float4 stride between h rows

    for (int i = g; i < total; i += 16) {
        unsigned it = items[i];
        int ci = it >> 8, e = it & 255;
        unsigned ent = lists[(size_t)(b * NXY + xy0 + ci) * CAP + e];
        int cid = ent & 0xffff;
        unsigned hmask = ent >> 16;
        int w = cid % NFW; int t2 = cid / NFW;
        int d = t2 % ND_;  t2 /= ND_;
        int n = t2 % NN_;                     // b is pinned by the cell id
        const float4* xp = (const float4*)
            (x + (((size_t)((b * NN_ + n) * ND_ + d) * NFH) * NFW + w) * NC) + l;

        float4 a = make_float4(0.f, 0.f, 0.f, 0.f);
        float4 v[8];
        #pragma unroll
        for (int j = 0; j < 8; ++j) v[j] = xp[j * HS];
        #pragma unroll
        for (int j = 0; j < 8; ++j) {
            float m = ((hmask >> j) & 1) ? 1.0f : 0.0f;
            a.x += v[j].x * m; a.y += v[j].y * m;
            a.z += v[j].z * m; a.w += v[j].w * m;
        }
        #pragma unroll
        for (int j = 0; j < 8; ++j) v[j] = xp[(8 + j) * HS];
        #pragma unroll
        for (int j = 0; j < 8; ++j) {
            float m = ((hmask >> (8 + j)) & 1) ? 1.0f : 0.0f;
            a.x += v[j].x * m; a.y += v[j].y * m;
            a.z += v[j].z * m; a.w += v[j].w * m;
        }

        float* tp = (float*)&tile[ci * 16 + (l ^ ((ci >> 2) & 15))];
        atomicAdd(tp + 0, a.x);   // ds_add_f32, no return
        atomicAdd(tp + 1, a.y);
        atomicAdd(tp + 2, a.z);
        atomicAdd(tp + 3, a.w);
    }
    __syncthreads();

    int lane = threadIdx.x & 63, wv = threadIdx.x >> 6;
    int q = lane & 15, lh = lane >> 4, i0 = q << 2;
    #pragma unroll
    for (int s = 0; s < 4; ++s) {
        int c  = s * 16 + wv * 4 + lh;        // covers 0..63 exactly once
        int c4 = c >> 2, cr = c & 3;
        float4 vv;
        vv.x = ((const float*)&tile[(i0 + 0) * 16 + (c4 ^ q)])[cr];
        vv.y = ((const float*)&tile[(i0 + 1) * 16 + (c4 ^ q)])[cr];
        vv.z = ((const float*)&tile[(i0 + 2) * 16 + (c4 ^ q)])[cr];
        vv.w = ((const float*)&tile[(i0 + 3) * 16 + (c4 ^ q)])[cr];
        *(float4*)(out + ((size_t)(b * NC + c)) * NXY + xy0 + i0) = vv;
    }
}

// ---------------- fallback (ws too small): direct-atomic path ----------------
__global__ __launch_bounds__(256) void col_pool_direct(const float* __restrict__ x,
                                                       const float* __restrict__ mats,
                                                       float* __restrict__ dst) {
    int cid = blockIdx.x * 8 + (threadIdx.x >> 5);
    int sub = threadIdx.x & 31;
    int l   = sub & 15;
    int hh  = sub >> 4;
    int w = cid % NFW; int t = cid / NFW;
    int d = t % ND_;   t /= ND_;
    int n = t % NN_;   int b = t / NN_;

    int myidx = compute_idx(b, n, d, l, w, mats);
    int idx8[8];
    #pragma unroll
    for (int j = 0; j < 8; ++j) idx8[j] = __shfl(myidx, hh * 8 + j, 32);

    int vmax = myidx;
    #pragma unroll
    for (int k = 1; k < 16; k <<= 1) vmax = max(vmax, __shfl_xor(vmax, k, 16));
    if (vmax < 0) return;

    const float4* xp = (const float4*)
        (x + (((size_t)((b * NN_ + n) * ND_ + d) * NFH) * NFW + w) * NC) + l;
    const int HSTRIDE = NFW * (NC / 4);
    #pragma unroll
    for (int j = 0; j < 8; ++j) {
        if (idx8[j] >= 0) {
            float4 v = xp[(hh * 8 + j) * HSTRIDE];
            int bb = idx8[j] / NXY, xy = idx8[j] % NXY;
            float* o = dst + ((size_t)(bb * NC + l * 4)) * NXY + xy;
            hw_fadd(o,           v.x);
            hw_fadd(o + NXY,     v.y);
            hw_fadd(o + 2 * NXY, v.z);
            hw_fadd(o + 3 * NXY, v.w);
        }
    }
}

extern "C" void kernel_launch(void* const* d_in, const int* in_sizes, int n_in,
                              void* d_out, int out_size, void* d_ws, size_t ws_size,
                              hipStream_t stream) {
    (void)in_sizes; (void)n_in; (void)out_size;
    const float* x          = (const float*)d_in[0];
    const float* rots       = (const float*)d_in[1];
    const float* trans      = (const float*)d_in[2];
    const float* intrins    = (const float*)d_in[3];
    const float* post_rots  = (const float*)d_in[4];
    const float* post_trans = (const float*)d_in[5];
    float* out = (float*)d_out;

    const size_t need = ((size_t)NCELL * (CAP + 1) + 1024) * sizeof(int);  // ~31.4 MB

    if (ws_size >= need) {
        int*      cnt   = (int*)d_ws;
        unsigned* lists = (unsigned*)(cnt + NCELL);
        float*    mats  = (float*)(lists + (size_t)NCELL * CAP);
        setup_kernel<<<1, 32, 0, stream>>>(rots, trans, intrins, post_rots, post_trans, mats);
        hipMemsetAsync(cnt, 0, (size_t)NCELL * sizeof(int), stream);   // ws re-poisoned each call
        build_lists<<<(NCOL + 255) / 256, 256, 0, stream>>>(mats, cnt, lists);
        gather_bev<<<dim3(NXY / 64, NB), 256, 0, stream>>>(x, cnt, lists, out);
    } else {
        float* mats = (float*)d_ws;   // 576 floats
        setup_kernel<<<1, 32, 0, stream>>>(rots, trans, intrins, post_rots, post_trans, mats);
        hipMemsetAsync(out, 0, (size_t)NB * NC * NXY * sizeof(float), stream);
        col_pool_direct<<<NCOL / 8, 256, 0, stream>>>(x, mats, out);
    }
}